// Round 1
// baseline (51.415 us; speedup 1.0000x reference)
//
#include <hip/hip_runtime.h>
#include <cfloat>
#include <cmath>
#include <cstdint>

#define VV 50257
#define NT 1024
#define NBUCK 4096
#define CAP 1024
#define BITW ((VV + 31) / 32)

__device__ __forceinline__ unsigned fmono(float f) {
    unsigned b = __float_as_uint(f);
    return b ^ (((int)b < 0) ? 0xFFFFFFFFu : 0x80000000u);
}

__global__ __launch_bounds__(NT) void PromptProcessor_58351425683655_kernel(
    const float* __restrict__ logits, const int* __restrict__ prev,
    const float* __restrict__ u, const float* __restrict__ toppp,
    const float* __restrict__ rpp, const float* __restrict__ tempp,
    const int* __restrict__ topkp, float* __restrict__ out_idx,
    float* __restrict__ out_probs, int Hp)
{
    __shared__ unsigned bitmap[BITW];     // prev-token membership bits
    __shared__ unsigned hist[NBUCK];      // monotonic-float-bit histogram
    __shared__ unsigned scan_s[NT];       // suffix-sum scratch
    __shared__ float cand_v[CAP];
    __shared__ int   cand_i[CAP];
    __shared__ float red_m[NT / 64];
    __shared__ float red_s[NT / 64];
    __shared__ float sM, sS;
    __shared__ int sT, sCnt;

    const int row = blockIdx.x;
    const int tid = threadIdx.x;
    const float top_p = toppp[0];
    const float rp = rpp[0];
    const float inv_rp = 1.0f / rp;
    const float temp = tempp[0];
    int K = topkp[0];
    K = min(max(K, 1), 64);

    for (int i = tid; i < BITW; i += NT) bitmap[i] = 0u;
    for (int i = tid; i < NBUCK; i += NT) hist[i] = 0u;
    if (tid == 0) { sT = 0; sCnt = 0; }
    __syncthreads();

    // ---- build prev-token bitmap (penalty is idempotent w.r.t. duplicates) ----
    const int* prow = prev + (size_t)row * Hp;
    for (int i = tid; i < Hp; i += NT) {
        int t = prow[i];
        atomicOr(&bitmap[t >> 5], 1u << (t & 31));
    }
    __syncthreads();

    // ---- pass 1: penalized value, online max/sum (global softmax), histogram ----
    const float* lrow = logits + (size_t)row * VV;
    float m = -INFINITY, s = 0.0f;
    for (int i = tid; i < VV; i += NT) {
        float l = lrow[i];
        if ((bitmap[i >> 5] >> (i & 31)) & 1u)
            l = (l < 0.0f) ? l * rp : l * inv_rp;
        atomicAdd(&hist[fmono(l) >> 20], 1u);
        if (l <= m) {
            s += __expf(l - m);
        } else {
            s = s * __expf(m - l) + 1.0f;
            m = l;
        }
    }
    #pragma unroll
    for (int off = 32; off; off >>= 1) {
        float om = __shfl_down(m, off);
        float os = __shfl_down(s, off);
        float nm = fmaxf(m, om);
        s = s * __expf(m - nm) + os * __expf(om - nm);
        m = nm;
    }
    const int wid = tid >> 6;
    if ((tid & 63) == 0) { red_m[wid] = m; red_s[wid] = s; }
    __syncthreads();
    if (tid < 64) {
        const int NW = NT / 64;
        float mm = (tid < NW) ? red_m[tid] : -FLT_MAX;
        float ss = (tid < NW) ? red_s[tid] : 0.0f;
        #pragma unroll
        for (int off = NW / 2; off; off >>= 1) {
            float om = __shfl_down(mm, off);
            float os = __shfl_down(ss, off);
            float nm = fmaxf(mm, om);
            ss = ss * __expf(mm - nm) + os * __expf(om - nm);
            mm = nm;
        }
        if (tid == 0) { sM = mm; sS = ss; }
    }

    // ---- find threshold bucket: suffix-sum over 4096 buckets (4/thread) ----
    unsigned c = hist[tid * 4] + hist[tid * 4 + 1] + hist[tid * 4 + 2] + hist[tid * 4 + 3];
    scan_s[tid] = c;
    __syncthreads();
    for (int off = 1; off < NT; off <<= 1) {
        unsigned v2 = scan_s[tid] + ((tid + off < NT) ? scan_s[tid + off] : 0u);
        __syncthreads();
        scan_s[tid] = v2;
        __syncthreads();
    }
    {
        unsigned mySuf = scan_s[tid];
        unsigned nxtSuf = (tid + 1 < NT) ? scan_s[tid + 1] : 0u;
        if (mySuf >= (unsigned)K && nxtSuf < (unsigned)K) {
            unsigned above = nxtSuf;
            for (int j = tid * 4 + 3; j >= tid * 4; --j) {
                unsigned h = hist[j];
                if (above + h >= (unsigned)K) { sT = j; break; }
                above += h;
            }
        }
    }
    __syncthreads();
    const int T = sT;

    // ---- pass 2: collect candidates >= threshold bucket ----
    for (int i = tid; i < VV; i += NT) {
        float l = lrow[i];
        if ((bitmap[i >> 5] >> (i & 31)) & 1u)
            l = (l < 0.0f) ? l * rp : l * inv_rp;
        if ((int)(fmono(l) >> 20) >= T) {
            int p = atomicAdd(&sCnt, 1);
            if (p < CAP) { cand_v[p] = l; cand_i[p] = i; }
        }
    }
    __syncthreads();
    const int cnt = min(sCnt, CAP);
    int P = 64;
    while (P < cnt) P <<= 1;   // sort size: pow2 >= cnt, >= 64
    if (tid >= cnt && tid < P) { cand_v[tid] = -FLT_MAX; cand_i[tid] = VV + tid; }
    __syncthreads();

    // ---- bitonic sort descending (tie: lower index first, matches stable argsort) ----
    for (int k2 = 2; k2 <= P; k2 <<= 1) {
        for (int j = k2 >> 1; j > 0; j >>= 1) {
            int i = tid, ixj = i ^ j;
            if (ixj > i && ixj < P) {
                float a = cand_v[i], b = cand_v[ixj];
                int ai = cand_i[i], bi = cand_i[ixj];
                bool iFirst = (a > b) || (a == b && ai < bi);
                bool desc = ((i & k2) == 0);
                if (desc ? !iFirst : iFirst) {
                    cand_v[i] = b; cand_v[ixj] = a;
                    cand_i[i] = bi; cand_i[ixj] = ai;
                }
            }
            __syncthreads();
        }
    }

    // ---- wave 0: top-p cutoff, temperature softmax, scatter, gumbel argmax ----
    if (tid < 64) {
        const int lane = tid;
        const float M = sM, S = sS;
        float v = cand_v[lane];
        int ci = cand_i[lane];
        bool act = (lane < K) && (lane < cnt);
        float e = act ? expf(v - M) / S : 0.0f;
        float cum = e;
        #pragma unroll
        for (int off = 1; off < 64; off <<= 1) {
            float pv = __shfl_up(cum, off);
            if (lane >= off) cum += pv;
        }
        unsigned long long bal = __ballot(act && (cum <= top_p));
        int n = (int)__popcll(bal);
        if (n < 1) n = 1;   // rank-0 always kept
        const float v0 = cand_v[0];
        const float invT = 1.0f / fmaxf(temp, 1e-5f);
        bool keep = (lane < n);
        float w = keep ? expf((v - v0) * invT) : 0.0f;
        float Z = w;
        #pragma unroll
        for (int off = 32; off; off >>= 1) Z += __shfl_xor(Z, off);
        float p = keep ? (w / Z) : 0.0f;
        if (keep) out_probs[(size_t)row * VV + ci] = p;
        float ratio = -1.0f;
        if (keep) ratio = p / (-logf(u[(size_t)row * VV + ci]));
        int bi = keep ? ci : 0x7FFFFFFF;
        #pragma unroll
        for (int off = 32; off; off >>= 1) {
            float orat = __shfl_xor(ratio, off);
            int oidx = __shfl_xor(bi, off);
            if (orat > ratio || (orat == ratio && oidx < bi)) { ratio = orat; bi = oidx; }
        }
        if (lane == 0) out_idx[row] = (float)bi;
    }
}

extern "C" void kernel_launch(void* const* d_in, const int* in_sizes, int n_in,
                              void* d_out, int out_size, void* d_ws, size_t ws_size,
                              hipStream_t stream) {
    const float* logits = (const float*)d_in[0];
    const int*   prev   = (const int*)d_in[1];
    const float* u      = (const float*)d_in[2];
    const float* topp   = (const float*)d_in[3];
    const float* rp     = (const float*)d_in[4];
    const float* temp   = (const float*)d_in[5];
    const int*   topk   = (const int*)d_in[6];

    const int B  = in_sizes[0] / VV;
    const int Hp = in_sizes[1] / B;

    float* out = (float*)d_out;
    // probs are sparse (<=64 nonzeros/row): zero everything, then scatter.
    hipMemsetAsync(d_out, 0, (size_t)out_size * sizeof(float), stream);
    PromptProcessor_58351425683655_kernel<<<B, NT, 0, stream>>>(
        logits, prev, u, topp, rp, temp, topk, out, out + B, Hp);
}